// Round 1
// baseline (429.988 us; speedup 1.0000x reference)
//
#include <hip/hip_runtime.h>
#include <hip/hip_bf16.h>

#define B_ 4
#define T_ 256
#define S_ 256
#define D_ 512

// ---------------------------------------------------------------------------
// Tiled fp32 GEMM: C[M x N] = A[M x K] @ Bm[K x N] (+ bias), row-major.
// A is given as two pointers: rows of A are A1 (k < KA) and A2 (k >= KA),
// each with row stride KA. This lets us do [mix, output] @ Wout without
// materializing the concatenation. A2 == nullptr means K == KA.
// 64x64 block tile, BK=16, 256 threads, 4x4 micro-tile per thread.
// ---------------------------------------------------------------------------
__global__ __launch_bounds__(256) void gemm_tiled(
    const float* __restrict__ A1,
    const float* __restrict__ A2,
    const float* __restrict__ Bm,
    const float* __restrict__ bias,
    float* __restrict__ C,
    int M, int N, int K, int KA)
{
    __shared__ float As[16][68];  // [k][m], padded
    __shared__ float Bs[16][68];  // [k][n], padded

    const int bm = blockIdx.y * 64;
    const int bn = blockIdx.x * 64;
    const int tid = threadIdx.x;
    const int tx = tid % 16;   // -> n
    const int ty = tid / 16;   // -> m

    float acc[4][4] = {};

    for (int k0 = 0; k0 < K; k0 += 16) {
        // uniform branch: each 16-wide k-tile lies entirely in A1 or A2
        const float* src;
        int kbase;
        if (k0 < KA) { src = A1; kbase = k0; }
        else         { src = A2; kbase = k0 - KA; }

        __syncthreads();
        // A tile: 64 rows x 16 k (1024 elems, 4 per thread)
        #pragma unroll
        for (int i = 0; i < 4; ++i) {
            int idx = tid + i * 256;
            int r = idx >> 4, c = idx & 15;
            As[c][r] = src[(size_t)(bm + r) * KA + kbase + c];
        }
        // B tile: 16 k x 64 n (coalesced: consecutive threads -> consecutive n)
        #pragma unroll
        for (int i = 0; i < 4; ++i) {
            int idx = tid + i * 256;
            int r = idx >> 6, c = idx & 63;
            Bs[r][c] = Bm[(size_t)(k0 + r) * N + bn + c];
        }
        __syncthreads();

        #pragma unroll
        for (int kk = 0; kk < 16; ++kk) {
            float a[4], b[4];
            #pragma unroll
            for (int i = 0; i < 4; ++i) a[i] = As[kk][ty * 4 + i];
            #pragma unroll
            for (int j = 0; j < 4; ++j) b[j] = Bs[kk][tx * 4 + j];
            #pragma unroll
            for (int i = 0; i < 4; ++i)
                #pragma unroll
                for (int j = 0; j < 4; ++j)
                    acc[i][j] += a[i] * b[j];
        }
    }

    #pragma unroll
    for (int i = 0; i < 4; ++i) {
        int row = bm + ty * 4 + i;
        #pragma unroll
        for (int j = 0; j < 4; ++j) {
            int col = bn + tx * 4 + j;
            float val = acc[i][j];
            if (bias) val += bias[col];
            C[(size_t)row * N + col] = val;
        }
    }
}

// ---------------------------------------------------------------------------
// Fused additive-attention score + masked softmax + mix.
// One block (256 threads) per (b, t). Thread s owns score[b,t,s].
//   score[s] = sum_d v[d] * tanh(wq[b,t,d] + uh[b,s,d])
//   attn = exp(score - max_all) * (1-mask) / sum
//   mix[b,t,d] = sum_s attn[s] * context[b,s,d]   (each thread: d=tid, tid+256)
// ---------------------------------------------------------------------------
__device__ __forceinline__ float tanh_fast(float x) {
    // tanh(x) = 1 - 2/(exp(2x)+1); saturates correctly via inf/0 behavior
    float e = __expf(2.0f * x);
    return 1.0f - 2.0f / (e + 1.0f);
}

__global__ __launch_bounds__(256) void attn_fused(
    const float* __restrict__ wq,       // (B,T,D)
    const float* __restrict__ uh,       // (B,S,D)
    const float* __restrict__ context,  // (B,S,D)
    const int*   __restrict__ mask,     // (B,S)
    const float* __restrict__ v,        // (D)
    float* __restrict__ attn_out,       // (B,T,S)
    float* __restrict__ mix)            // (B,T,D)
{
    const int bt = blockIdx.x;
    const int b = bt / T_;
    const int tid = threadIdx.x;  // s index

    __shared__ float wq_s[D_];
    __shared__ float v_s[D_];
    __shared__ float uh_s[S_][33];  // 32-wide d-chunk, pad -> conflict-free
    __shared__ float red[256];

    for (int i = tid; i < D_; i += 256) {
        wq_s[i] = wq[(size_t)bt * D_ + i];
        v_s[i]  = v[i];
    }
    __syncthreads();

    float score = 0.0f;
    for (int d0 = 0; d0 < D_; d0 += 32) {
        __syncthreads();  // previous chunk's reads done
        // cooperative, coalesced load of uh[b, :, d0:d0+32]
        #pragma unroll
        for (int i = 0; i < 32; ++i) {
            int idx = tid + i * 256;
            int s = idx >> 5, dk = idx & 31;
            uh_s[s][dk] = uh[((size_t)b * S_ + s) * D_ + d0 + dk];
        }
        __syncthreads();
        #pragma unroll
        for (int dk = 0; dk < 32; ++dk) {
            float x = wq_s[d0 + dk] + uh_s[tid][dk];
            score += v_s[d0 + dk] * tanh_fast(x);
        }
    }

    // block max over all 256 scores (reference maxes over ALL s, pre-mask)
    red[tid] = score;
    __syncthreads();
    for (int off = 128; off > 0; off >>= 1) {
        if (tid < off) red[tid] = fmaxf(red[tid], red[tid + off]);
        __syncthreads();
    }
    float mx = red[0];
    __syncthreads();

    float keep = 1.0f - (float)mask[b * S_ + tid];
    float p = __expf(score - mx) * keep;

    red[tid] = p;
    __syncthreads();
    for (int off = 128; off > 0; off >>= 1) {
        if (tid < off) red[tid] += red[tid + off];
        __syncthreads();
    }
    float denom = red[0];
    __syncthreads();

    float a = p / denom;
    attn_out[(size_t)bt * S_ + tid] = a;

    // share attn across block for the mix GEMV
    red[tid] = a;
    __syncthreads();

    float m0 = 0.0f, m1 = 0.0f;
    const float* ctx_b = context + (size_t)b * S_ * D_;
    for (int s = 0; s < S_; ++s) {
        float as = red[s];                    // LDS broadcast
        m0 += as * ctx_b[(size_t)s * D_ + tid];        // coalesced
        m1 += as * ctx_b[(size_t)s * D_ + tid + 256];  // coalesced
    }
    mix[(size_t)bt * D_ + tid]       = m0;
    mix[(size_t)bt * D_ + tid + 256] = m1;
}

extern "C" void kernel_launch(void* const* d_in, const int* in_sizes, int n_in,
                              void* d_out, int out_size, void* d_ws, size_t ws_size,
                              hipStream_t stream) {
    const float* output  = (const float*)d_in[0];
    const float* context = (const float*)d_in[1];
    const int*   mask    = (const int*)d_in[2];
    const float* Wq      = (const float*)d_in[3];
    const float* bq      = (const float*)d_in[4];
    const float* Wc      = (const float*)d_in[5];
    const float* v       = (const float*)d_in[6];
    const float* Wout    = (const float*)d_in[7];
    const float* bout    = (const float*)d_in[8];

    float* out  = (float*)d_out;                       // (B,T,D)
    float* attn = out + (size_t)B_ * T_ * D_;          // (B,T,S)

    float* wq  = (float*)d_ws;                         // (B,T,D) 2 MB
    float* uh  = wq + (size_t)B_ * T_ * D_;            // (B,S,D) 2 MB
    float* mix = uh + (size_t)B_ * S_ * D_;            // (B,T,D) 2 MB

    dim3 blk(256);
    dim3 g_gemm(D_ / 64, (B_ * T_) / 64);  // N/64=8, M/64=16

    // wq = output @ Wq + bq
    gemm_tiled<<<g_gemm, blk, 0, stream>>>(output, nullptr, Wq, bq, wq,
                                           B_ * T_, D_, D_, D_);
    // uh = context @ Wc
    gemm_tiled<<<g_gemm, blk, 0, stream>>>(context, nullptr, Wc, nullptr, uh,
                                           B_ * S_, D_, D_, D_);
    // fused score + softmax + mix
    attn_fused<<<dim3(B_ * T_), blk, 0, stream>>>(wq, uh, context, mask, v,
                                                  attn, mix);
    // out = [mix, output] @ Wout + bout
    gemm_tiled<<<g_gemm, blk, 0, stream>>>(mix, output, Wout, bout, out,
                                           B_ * T_, D_, 2 * D_, D_);
}

// Round 2
// 258.985 us; speedup vs baseline: 1.6603x; 1.6603x over previous
//
#include <hip/hip_runtime.h>
#include <hip/hip_bf16.h>

#define B_ 4
#define T_ 256
#define S_ 256
#define D_ 512
#define TB 2   // t's per attention block

// ---------------------------------------------------------------------------
// Tiled fp32 GEMM: C = A @ Bm (+ bias). A rows come from A1 (k<KA) / A2
// (k>=KA), each row-stride KA (for the [mix, output] concat). blockIdx.z
// selects one of two independent GEMM argument sets so two same-shape GEMMs
// run in a single dispatch (fills all 256 CUs; one alone is only 128 blocks).
// ---------------------------------------------------------------------------
struct GemmArgs {
    const float* A1; const float* A2; const float* Bm; const float* bias; float* C;
};

__global__ __launch_bounds__(256) void gemm_tiled(
    GemmArgs g0, GemmArgs g1, int M, int N, int K, int KA)
{
    GemmArgs g = (blockIdx.z == 0) ? g0 : g1;

    __shared__ float As[16][68];  // [k][m], padded
    __shared__ float Bs[16][68];  // [k][n], padded

    const int bm = blockIdx.y * 64;
    const int bn = blockIdx.x * 64;
    const int tid = threadIdx.x;
    const int tx = tid % 16;   // -> n
    const int ty = tid / 16;   // -> m

    float acc[4][4] = {};

    for (int k0 = 0; k0 < K; k0 += 16) {
        const float* src;
        int kbase;
        if (k0 < KA) { src = g.A1; kbase = k0; }
        else         { src = g.A2; kbase = k0 - KA; }

        __syncthreads();
        #pragma unroll
        for (int i = 0; i < 4; ++i) {
            int idx = tid + i * 256;
            int r = idx >> 4, c = idx & 15;
            As[c][r] = src[(size_t)(bm + r) * KA + kbase + c];
        }
        #pragma unroll
        for (int i = 0; i < 4; ++i) {
            int idx = tid + i * 256;
            int r = idx >> 6, c = idx & 63;
            Bs[r][c] = g.Bm[(size_t)(k0 + r) * N + bn + c];
        }
        __syncthreads();

        #pragma unroll
        for (int kk = 0; kk < 16; ++kk) {
            float a[4], b[4];
            #pragma unroll
            for (int i = 0; i < 4; ++i) a[i] = As[kk][ty * 4 + i];
            #pragma unroll
            for (int j = 0; j < 4; ++j) b[j] = Bs[kk][tx * 4 + j];
            #pragma unroll
            for (int i = 0; i < 4; ++i)
                #pragma unroll
                for (int j = 0; j < 4; ++j)
                    acc[i][j] += a[i] * b[j];
        }
    }

    #pragma unroll
    for (int i = 0; i < 4; ++i) {
        int row = bm + ty * 4 + i;
        #pragma unroll
        for (int j = 0; j < 4; ++j) {
            int col = bn + tx * 4 + j;
            float val = acc[i][j];
            if (g.bias) val += g.bias[col];
            g.C[(size_t)row * N + col] = val;
        }
    }
}

// ---------------------------------------------------------------------------
// Fused additive-attention score + masked softmax + mix.
// One block per TB consecutive t's of one b. Thread tid owns s = tid.
// tanh identity: tanh(x) = 1 - 2/(exp2(c*x)+1), c = 2*log2(e). We stage
// c*wq and c*uh so the inner loop is add+exp2+add+rcp+fma per (t,s,d).
// score = Vsum - 2 * sum_d v[d]*r[d]  (Vsum = sum v, hoisted out).
// ---------------------------------------------------------------------------
__global__ __launch_bounds__(256) void attn_fused(
    const float* __restrict__ wq,       // (B,T,D)
    const float* __restrict__ uh,       // (B,S,D)
    const float* __restrict__ context,  // (B,S,D)
    const int*   __restrict__ mask,     // (B,S)
    const float* __restrict__ v,        // (D)
    float* __restrict__ attn_out,       // (B,T,S)
    float* __restrict__ mix)            // (B,T,D)
{
    const int bg  = blockIdx.x;
    const int b   = bg / (T_ / TB);
    const int t0  = (bg % (T_ / TB)) * TB;
    const int tid = threadIdx.x;        // s index

    const float C2 = 2.885390081777926f;  // 2*log2(e)

    __shared__ float  wq_s[TB][D_];     // pre-scaled by C2
    __shared__ float  v_s[D_];
    __shared__ float  uh_s[S_][33];     // 32-wide d-chunk, pre-scaled; pad->2-way max
    __shared__ float2 red[256];
    __shared__ float  a_s[TB][S_];

    for (int i = tid; i < D_; i += 256) {
        v_s[i] = v[i];
        #pragma unroll
        for (int j = 0; j < TB; ++j)
            wq_s[j][i] = C2 * wq[(size_t)(b * T_ + t0 + j) * D_ + i];
    }
    __syncthreads();

    // Vsum = sum_d v[d] (block tree reduce, once)
    red[tid].x = v_s[tid] + v_s[tid + 256];
    __syncthreads();
    for (int off = 128; off > 0; off >>= 1) {
        if (tid < off) red[tid].x += red[tid + off].x;
        __syncthreads();
    }
    const float Vsum = red[0].x;
    __syncthreads();

    float acc0 = 0.0f, acc1 = 0.0f;
    const float* uh_b = uh + (size_t)b * S_ * D_;

    for (int d0 = 0; d0 < D_; d0 += 32) {
        __syncthreads();  // previous chunk's reads done
        // stage uh[b, :, d0:d0+32] scaled by C2: 2048 float4, 8 per thread
        #pragma unroll
        for (int i = 0; i < 8; ++i) {
            int idx = tid + i * 256;       // [0,2048)
            int s = idx >> 3, q = idx & 7; // q: float4 within 32-wide chunk
            float4 val = *(const float4*)(uh_b + (size_t)s * D_ + d0 + 4 * q);
            uh_s[s][4 * q + 0] = C2 * val.x;
            uh_s[s][4 * q + 1] = C2 * val.y;
            uh_s[s][4 * q + 2] = C2 * val.z;
            uh_s[s][4 * q + 3] = C2 * val.w;
        }
        __syncthreads();

        #pragma unroll 8
        for (int dk = 0; dk < 32; ++dk) {
            float u  = uh_s[tid][dk];
            float vv = v_s[d0 + dk];
            float x0 = wq_s[0][d0 + dk] + u;
            float x1 = wq_s[1][d0 + dk] + u;
            float r0 = __builtin_amdgcn_rcpf(__builtin_amdgcn_exp2f(x0) + 1.0f);
            float r1 = __builtin_amdgcn_rcpf(__builtin_amdgcn_exp2f(x1) + 1.0f);
            acc0 = fmaf(vv, r0, acc0);
            acc1 = fmaf(vv, r1, acc1);
        }
    }

    float sc0 = Vsum - 2.0f * acc0;
    float sc1 = Vsum - 2.0f * acc1;

    // block max over all 256 s (reference maxes over ALL positions, pre-mask)
    red[tid] = make_float2(sc0, sc1);
    __syncthreads();
    for (int off = 128; off > 0; off >>= 1) {
        if (tid < off) {
            red[tid].x = fmaxf(red[tid].x, red[tid + off].x);
            red[tid].y = fmaxf(red[tid].y, red[tid + off].y);
        }
        __syncthreads();
    }
    float2 mx = red[0];
    __syncthreads();

    float keep = 1.0f - (float)mask[b * S_ + tid];
    float p0 = __expf(sc0 - mx.x) * keep;
    float p1 = __expf(sc1 - mx.y) * keep;

    red[tid] = make_float2(p0, p1);
    __syncthreads();
    for (int off = 128; off > 0; off >>= 1) {
        if (tid < off) {
            red[tid].x += red[tid + off].x;
            red[tid].y += red[tid + off].y;
        }
        __syncthreads();
    }
    float2 denom = red[0];
    __syncthreads();

    float a0 = p0 * __builtin_amdgcn_rcpf(denom.x);
    float a1 = p1 * __builtin_amdgcn_rcpf(denom.y);
    attn_out[(size_t)(b * T_ + t0 + 0) * S_ + tid] = a0;
    attn_out[(size_t)(b * T_ + t0 + 1) * S_ + tid] = a1;

    a_s[0][tid] = a0;
    a_s[1][tid] = a1;
    __syncthreads();

    // mix[b,t,:] = sum_s a[s] * context[b,s,:]; thread owns d = {2tid, 2tid+1}
    const float2* ctx2 = (const float2*)(context + (size_t)b * S_ * D_);
    float2 m0 = make_float2(0.f, 0.f), m1 = make_float2(0.f, 0.f);
    #pragma unroll 4
    for (int s = 0; s < S_; ++s) {
        float2 c = ctx2[(size_t)s * (D_ / 2) + tid];
        float u0 = a_s[0][s], u1 = a_s[1][s];
        m0.x = fmaf(u0, c.x, m0.x);  m0.y = fmaf(u0, c.y, m0.y);
        m1.x = fmaf(u1, c.x, m1.x);  m1.y = fmaf(u1, c.y, m1.y);
    }
    float2* mix2 = (float2*)mix;
    mix2[(size_t)(b * T_ + t0 + 0) * (D_ / 2) + tid] = m0;
    mix2[(size_t)(b * T_ + t0 + 1) * (D_ / 2) + tid] = m1;
}

extern "C" void kernel_launch(void* const* d_in, const int* in_sizes, int n_in,
                              void* d_out, int out_size, void* d_ws, size_t ws_size,
                              hipStream_t stream) {
    const float* output  = (const float*)d_in[0];
    const float* context = (const float*)d_in[1];
    const int*   mask    = (const int*)d_in[2];
    const float* Wq      = (const float*)d_in[3];
    const float* bq      = (const float*)d_in[4];
    const float* Wc      = (const float*)d_in[5];
    const float* v       = (const float*)d_in[6];
    const float* Wout    = (const float*)d_in[7];
    const float* bout    = (const float*)d_in[8];

    float* out  = (float*)d_out;                       // (B,T,D)
    float* attn = out + (size_t)B_ * T_ * D_;          // (B,T,S)

    float* wq  = (float*)d_ws;                         // (B,T,D) 2 MB
    float* uh  = wq + (size_t)B_ * T_ * D_;            // (B,S,D) 2 MB
    float* mix = uh + (size_t)B_ * S_ * D_;            // (B,T,D) 2 MB

    dim3 blk(256);

    // wq = output @ Wq + bq  AND  uh = context @ Wc, one dispatch (grid.z=2)
    GemmArgs gq = { output,  nullptr, Wq, bq,      wq };
    GemmArgs gc = { context, nullptr, Wc, nullptr, uh };
    gemm_tiled<<<dim3(D_ / 64, (B_ * T_) / 64, 2), blk, 0, stream>>>(
        gq, gc, B_ * T_, D_, D_, D_);

    // fused score + softmax + mix
    attn_fused<<<dim3(B_ * T_ / TB), blk, 0, stream>>>(wq, uh, context, mask, v,
                                                       attn, mix);

    // out = [mix, output] @ Wout + bout
    GemmArgs go = { mix, output, Wout, bout, out };
    gemm_tiled<<<dim3(D_ / 64, (B_ * T_) / 64, 1), blk, 0, stream>>>(
        go, go, B_ * T_, D_, 2 * D_, D_);
}

// Round 3
// 158.214 us; speedup vs baseline: 2.7178x; 1.6369x over previous
//
#include <hip/hip_runtime.h>
#include <hip/hip_bf16.h>

#define B_ 4
#define T_ 256
#define S_ 256
#define D_ 512
#define TB 2   // t's per attention block

typedef __bf16 bf16x8 __attribute__((ext_vector_type(8)));
typedef float  floatx4 __attribute__((ext_vector_type(4)));

static __device__ __forceinline__ unsigned short f2bf(float x) {
    __hip_bfloat16 h = __float2bfloat16(x);
    return *reinterpret_cast<unsigned short*>(&h);
}

// ---------------------------------------------------------------------------
// prep: z=3 -> fp32->bf16 convert of output & context (linear, float4).
//       z=0,1,2 -> transpose+convert Wq, Wc, Wout into n-major bf16 (WT[n][k])
//       so MFMA B-fragments are contiguous 16B loads. 32x32 LDS tiles.
// ---------------------------------------------------------------------------
__global__ __launch_bounds__(256) void prep(
    const float* __restrict__ output, const float* __restrict__ context,
    const float* __restrict__ Wq, const float* __restrict__ Wc,
    const float* __restrict__ Wout,
    unsigned short* __restrict__ out_b, unsigned short* __restrict__ ctx_b,
    unsigned short* __restrict__ WqT, unsigned short* __restrict__ WcT,
    unsigned short* __restrict__ WoutT)
{
    const int tid = threadIdx.x;
    const int z = blockIdx.z;

    if (z == 3) {
        // 512 blocks * 256 threads; rep0 -> output, rep1 -> context (524288 each)
        size_t i = ((size_t)(blockIdx.y * gridDim.x + blockIdx.x) * 256 + tid) * 4;
        #pragma unroll
        for (int rep = 0; rep < 2; ++rep) {
            const float* src = rep ? context : output;
            unsigned short* dst = rep ? ctx_b : out_b;
            float4 v = *(const float4*)(src + i);
            ushort4 p;
            p.x = f2bf(v.x); p.y = f2bf(v.y); p.z = f2bf(v.z); p.w = f2bf(v.w);
            *(ushort4*)(dst + i) = p;
        }
        return;
    }

    const float* W; unsigned short* WT; int K;
    if      (z == 0) { W = Wq;   WT = WqT;   K = 512;  }
    else if (z == 1) { W = Wc;   WT = WcT;   K = 512;  }
    else             { W = Wout; WT = WoutT; K = 1024; }

    const int n0 = blockIdx.x * 32;
    const int k0 = blockIdx.y * 32;
    if (k0 >= K) return;

    __shared__ float tile[32][33];
    const int c = tid & 31, r = tid >> 5;  // 8 rows per pass
    #pragma unroll
    for (int i = 0; i < 4; ++i)
        tile[r + 8 * i][c] = W[(size_t)(k0 + r + 8 * i) * D_ + n0 + c];
    __syncthreads();
    #pragma unroll
    for (int i = 0; i < 4; ++i)
        WT[(size_t)(n0 + r + 8 * i) * K + k0 + c] = f2bf(tile[c][r + 8 * i]);
}

// ---------------------------------------------------------------------------
// Barrier-free MFMA bf16 GEMM: C[M x N] = A @ B (+bias), fp32 out.
// A row-major bf16 (rows from A1 for k<KA, A2 for k>=KA, row stride KA).
// BT is B transposed, n-major bf16 (BT[n][k], stride K) -> contiguous frags.
// Block = 4 waves; wave w computes rows [bm+16w, +16) x NT 16-wide n-tiles.
// Fragments loaded straight from global (L2-resident); no LDS, no barriers.
// A-frag: lane holds A[m=lane&15][k=quad*8+j]; B-frag: BT[n=lane&15][k=quad*8+j]
// D: col=lane&15, row=quad*4+reg  (verified layouts, m89/m120).
// ---------------------------------------------------------------------------
struct MArgs {
    const unsigned short* A1; const unsigned short* A2;
    const unsigned short* BT; const float* bias; float* C;
};

template<int NT, int K, int KA>
__global__ __launch_bounds__(256) void gemm_mfma(MArgs ga, MArgs gb, int N)
{
    MArgs g = (blockIdx.z == 0) ? ga : gb;
    const int tid  = threadIdx.x;
    const int wave = tid >> 6, lane = tid & 63;
    const int l15  = lane & 15, quad = lane >> 4;
    const int bm   = blockIdx.y * 64;
    const int bn   = blockIdx.x * (NT * 16);
    const int am   = bm + wave * 16 + l15;

    floatx4 acc[NT];
    #pragma unroll
    for (int nt = 0; nt < NT; ++nt) acc[nt] = (floatx4){0.f, 0.f, 0.f, 0.f};

    #pragma unroll 4
    for (int k0 = 0; k0 < K; k0 += 32) {
        const unsigned short* Ap =
            (k0 < KA) ? g.A1 + (size_t)am * KA + k0
                      : g.A2 + (size_t)am * KA + (k0 - KA);
        bf16x8 a = *(const bf16x8*)(Ap + quad * 8);
        #pragma unroll
        for (int nt = 0; nt < NT; ++nt) {
            bf16x8 b = *(const bf16x8*)(g.BT + (size_t)(bn + nt * 16 + l15) * K
                                        + k0 + quad * 8);
            acc[nt] = __builtin_amdgcn_mfma_f32_16x16x32_bf16(a, b, acc[nt], 0, 0, 0);
        }
    }

    #pragma unroll
    for (int nt = 0; nt < NT; ++nt) {
        int col = bn + nt * 16 + l15;
        float bv = g.bias ? g.bias[col] : 0.0f;
        #pragma unroll
        for (int r = 0; r < 4; ++r) {
            int row = bm + wave * 16 + quad * 4 + r;
            g.C[(size_t)row * N + col] = acc[nt][r] + bv;
        }
    }
}

// ---------------------------------------------------------------------------
// Fused additive-attention score + masked softmax + mix.
// One block per TB consecutive t's of one b; thread tid owns s = tid.
// tanh(x) = 1 - 2/(exp2(C2*x)+1), C2 = 2*log2(e); score = Vsum - 2*sum v*r.
// uh row read DIRECTLY from global (own row, float4, L2-resident) -> no
// staging barriers. wq/v read from uniform addresses (scalarizes to s_load).
// mix written as bf16 (feeds the MFMA out-GEMM).
// ---------------------------------------------------------------------------
__global__ __launch_bounds__(256) void attn_fused(
    const float* __restrict__ wq,       // (B,T,D)
    const float* __restrict__ uh,       // (B,S,D)
    const float* __restrict__ context,  // (B,S,D)
    const int*   __restrict__ mask,     // (B,S)
    const float* __restrict__ v,        // (D)
    float* __restrict__ attn_out,       // (B,T,S)
    unsigned short* __restrict__ mix_b) // (B,T,D) bf16
{
    const int bg  = blockIdx.x;
    const int b   = bg / (T_ / TB);
    const int t0  = (bg % (T_ / TB)) * TB;
    const int tid = threadIdx.x;        // s index

    const float C2 = 2.885390081777926f;  // 2*log2(e)

    __shared__ float2 red[256];
    __shared__ float  a_s[TB][S_];

    // Vsum = sum_d v[d]
    red[tid].x = v[tid] + v[tid + 256];
    __syncthreads();
    for (int off = 128; off > 0; off >>= 1) {
        if (tid < off) red[tid].x += red[tid + off].x;
        __syncthreads();
    }
    const float Vsum = red[0].x;
    __syncthreads();

    const float4* u4p = (const float4*)(uh + ((size_t)b * S_ + tid) * D_);
    const float4* w04 = (const float4*)(wq + (size_t)(b * T_ + t0) * D_);
    const float4* w14 = (const float4*)(wq + (size_t)(b * T_ + t0 + 1) * D_);
    const float4* v4p = (const float4*)v;

    float acc0 = 0.0f, acc1 = 0.0f;
    #pragma unroll 4
    for (int q = 0; q < D_ / 4; ++q) {
        float4 u  = u4p[q];
        float4 w0 = w04[q];
        float4 w1 = w14[q];
        float4 vv = v4p[q];
        #pragma unroll
        for (int j = 0; j < 4; ++j) {
            float uu = ((const float*)&u)[j];
            float x0 = C2 * (((const float*)&w0)[j] + uu);
            float x1 = C2 * (((const float*)&w1)[j] + uu);
            float r0 = __builtin_amdgcn_rcpf(__builtin_amdgcn_exp2f(x0) + 1.0f);
            float r1 = __builtin_amdgcn_rcpf(__builtin_amdgcn_exp2f(x1) + 1.0f);
            float vj = ((const float*)&vv)[j];
            acc0 = fmaf(vj, r0, acc0);
            acc1 = fmaf(vj, r1, acc1);
        }
    }

    float sc0 = Vsum - 2.0f * acc0;
    float sc1 = Vsum - 2.0f * acc1;

    // block max over ALL s (reference maxes pre-mask)
    red[tid] = make_float2(sc0, sc1);
    __syncthreads();
    for (int off = 128; off > 0; off >>= 1) {
        if (tid < off) {
            red[tid].x = fmaxf(red[tid].x, red[tid + off].x);
            red[tid].y = fmaxf(red[tid].y, red[tid + off].y);
        }
        __syncthreads();
    }
    float2 mx = red[0];
    __syncthreads();

    float keep = 1.0f - (float)mask[b * S_ + tid];
    float p0 = __expf(sc0 - mx.x) * keep;
    float p1 = __expf(sc1 - mx.y) * keep;

    red[tid] = make_float2(p0, p1);
    __syncthreads();
    for (int off = 128; off > 0; off >>= 1) {
        if (tid < off) {
            red[tid].x += red[tid + off].x;
            red[tid].y += red[tid + off].y;
        }
        __syncthreads();
    }
    float2 denom = red[0];
    __syncthreads();

    float a0 = p0 * __builtin_amdgcn_rcpf(denom.x);
    float a1 = p1 * __builtin_amdgcn_rcpf(denom.y);
    attn_out[(size_t)(b * T_ + t0 + 0) * S_ + tid] = a0;
    attn_out[(size_t)(b * T_ + t0 + 1) * S_ + tid] = a1;

    a_s[0][tid] = a0;
    a_s[1][tid] = a1;
    __syncthreads();

    // mix[b,t,:] = sum_s a[s] * context[b,s,:]; thread owns d = {2tid, 2tid+1}
    const float2* ctx2 = (const float2*)(context + (size_t)b * S_ * D_);
    float2 m0 = make_float2(0.f, 0.f), m1 = make_float2(0.f, 0.f);
    #pragma unroll 4
    for (int s = 0; s < S_; ++s) {
        float2 c = ctx2[(size_t)s * (D_ / 2) + tid];
        float u0 = a_s[0][s], u1 = a_s[1][s];
        m0.x = fmaf(u0, c.x, m0.x);  m0.y = fmaf(u0, c.y, m0.y);
        m1.x = fmaf(u1, c.x, m1.x);  m1.y = fmaf(u1, c.y, m1.y);
    }
    ushort2 p0s, p1s;
    p0s.x = f2bf(m0.x); p0s.y = f2bf(m0.y);
    p1s.x = f2bf(m1.x); p1s.y = f2bf(m1.y);
    *(ushort2*)(mix_b + (size_t)(b * T_ + t0 + 0) * D_ + 2 * tid) = p0s;
    *(ushort2*)(mix_b + (size_t)(b * T_ + t0 + 1) * D_ + 2 * tid) = p1s;
}

extern "C" void kernel_launch(void* const* d_in, const int* in_sizes, int n_in,
                              void* d_out, int out_size, void* d_ws, size_t ws_size,
                              hipStream_t stream) {
    const float* output  = (const float*)d_in[0];
    const float* context = (const float*)d_in[1];
    const int*   mask    = (const int*)d_in[2];
    const float* Wq      = (const float*)d_in[3];
    const float* bq      = (const float*)d_in[4];
    const float* Wc      = (const float*)d_in[5];
    const float* v       = (const float*)d_in[6];
    const float* Wout    = (const float*)d_in[7];
    const float* bout    = (const float*)d_in[8];

    float* out  = (float*)d_out;                       // (B,T,D)
    float* attn = out + (size_t)B_ * T_ * D_;          // (B,T,S)

    // workspace layout
    char* ws = (char*)d_ws;
    float* wq = (float*)ws;                                   // 2 MB fp32
    float* uh = (float*)(ws + (2u << 20));                    // 2 MB fp32
    unsigned short* out_b  = (unsigned short*)(ws + (4u << 20));  // 1 MB bf16
    unsigned short* ctx_b  = (unsigned short*)(ws + (5u << 20));  // 1 MB
    unsigned short* mix_b  = (unsigned short*)(ws + (6u << 20));  // 1 MB
    unsigned short* WqT    = (unsigned short*)(ws + (7u << 20));  // 0.5 MB
    unsigned short* WcT    = (unsigned short*)(ws + (7u << 20) + (512u << 10));
    unsigned short* WoutT  = (unsigned short*)(ws + (8u << 20));  // 1 MB

    dim3 blk(256);

    // convert + transpose everything to bf16 (one dispatch, z-sections)
    prep<<<dim3(16, 32, 4), blk, 0, stream>>>(
        output, context, Wq, Wc, Wout, out_b, ctx_b, WqT, WcT, WoutT);

    // wq = output@Wq + bq  AND  uh = context@Wc  (MFMA, one dispatch)
    MArgs gq = { out_b, out_b, WqT, bq,      wq };
    MArgs gc = { ctx_b, ctx_b, WcT, nullptr, uh };
    gemm_mfma<4, 512, 512><<<dim3(8, 16, 2), blk, 0, stream>>>(gq, gc, D_);

    // fused score + softmax + mix (mix -> bf16)
    attn_fused<<<dim3(B_ * T_ / TB), blk, 0, stream>>>(wq, uh, context, mask, v,
                                                       attn, mix_b);

    // out = [mix, output] @ Wout + bout  (MFMA, concat via A1/A2)
    MArgs go = { mix_b, out_b, WoutT, bout, out };
    gemm_mfma<2, 1024, 512><<<dim3(16, 16, 1), blk, 0, stream>>>(go, go, D_);
}